// Round 8
// baseline (144.448 us; speedup 1.0000x reference)
//
#include <hip/hip_runtime.h>

#define NTOK 4096   // H*W
#define PSTR 72     // padded LDS row stride (shorts)

typedef short bf16x8 __attribute__((ext_vector_type(8)));
typedef short bf16x4 __attribute__((ext_vector_type(4)));
typedef float f32x4 __attribute__((ext_vector_type(4)));

__device__ __forceinline__ short f2bf(float f) {          // RNE
  union { float f; unsigned u; } v; v.f = f;
  unsigned r = v.u + 0x7fffu + ((v.u >> 16) & 1u);
  return (short)(r >> 16);
}
__device__ __forceinline__ short f2bf_t(float f) {        // truncate (P matrix only)
  union { float f; unsigned u; } v; v.f = f;
  return (short)(v.u >> 16);
}
__device__ __forceinline__ float bf2f(short s) {
  union { unsigned u; float f; } v; v.u = ((unsigned)(unsigned short)s) << 16;
  return v.f;
}

struct PrepArgs {
  const float* w[6];
  short* wt;            // 6 x (64x64) bf16, W^T (d-major); w0,w3 pre-scaled by QSC
};

struct ConvArgs {
  const float* x;
  const short* wt;
  const float* bias[6];
  short* out[6];   // out[0]=qs, out[3]=qc (both pre-scaled); out[2]=vs_t (channel-major)
};

#define QSC (0.125f * 1.44269504088896f)

// ---- weight prep: W (f32, c-major) -> W^T (bf16, d-major); w0/w3 scaled by QSC ----
__global__ __launch_bounds__(256) void prep_w(PrepArgs p) {
  const int wi = blockIdx.x;
  const float* w = p.w[wi];
  short* o = p.wt + wi*4096;
  const int d = threadIdx.x & 63, cb = (threadIdx.x >> 6) * 16;
  const float sc = (wi == 0 || wi == 3) ? QSC : 1.f;
  bf16x8 v0, v1;
  for (int j=0;j<8;j++) {
    v0[j] = f2bf(w[(cb+j)*64 + d] * sc);
    v1[j] = f2bf(w[(cb+8+j)*64 + d] * sc);
  }
  *(bf16x8*)(o + d*64 + cb)     = v0;
  *(bf16x8*)(o + d*64 + cb + 8) = v1;
}

// ---- fused 1x1 conv: y = x @ W + b -> bf16; grid (256 token-tiles, 2 wi-halves) ----
__global__ __launch_bounds__(256) void conv_qkv(ConvArgs args) {
  __shared__ __align__(16) short lT[64*PSTR];   // transpose buf for vs_t (half 0 only)
  const int tid = threadIdx.x;
  const int wave = tid >> 6, lane = tid & 63;
  const int quad = lane >> 4, l16 = lane & 15;
  const int half = blockIdx.y;

  int row = blockIdx.x * 64 + wave*16 + l16;
  const float* xr = args.x + (size_t)row*64 + quad*8;
  f32x4 x0 = *(const f32x4*)xr;
  f32x4 x1 = *(const f32x4*)(xr+4);
  f32x4 x2 = *(const f32x4*)(xr+32);
  f32x4 x3 = *(const f32x4*)(xr+36);
  bf16x8 a0, a1;
  for (int j=0;j<4;j++){ a0[j]=f2bf(x0[j]); a0[4+j]=f2bf(x1[j]); a1[j]=f2bf(x2[j]); a1[4+j]=f2bf(x3[j]); }

  int orow_base = blockIdx.x*64 + wave*16 + quad*4;
  for (int j=0; j<3; j++) {
    const int wi = half*3 + j;
    const short* wtp = args.wt + wi*4096;
    for (int dt=0; dt<4; dt++) {
      bf16x8 b0 = *(const bf16x8*)(wtp + (dt*16+l16)*64 + quad*8);
      bf16x8 b1 = *(const bf16x8*)(wtp + (dt*16+l16)*64 + 32 + quad*8);
      f32x4 acc = {0.f,0.f,0.f,0.f};
      acc = __builtin_amdgcn_mfma_f32_16x16x32_bf16(a0, b0, acc, 0,0,0);
      acc = __builtin_amdgcn_mfma_f32_16x16x32_bf16(a1, b1, acc, 0,0,0);
      float bias = args.bias[wi][dt*16+l16];
      if (wi == 0 || wi == 3) bias *= QSC;
      if (wi != 2) {
        short* outp = args.out[wi];
        for (int r=0;r<4;r++)
          outp[(size_t)(orow_base + r)*64 + dt*16 + l16] = f2bf(acc[r] + bias);
      } else {
        for (int r=0;r<4;r++)
          lT[(dt*16+l16)*PSTR + wave*16 + quad*4 + r] = f2bf(acc[r] + bias);
      }
    }
  }
  if (half == 0) {
    __syncthreads();
    int b  = (blockIdx.x*64) >> 12;
    int n0 = (blockIdx.x*64) & 4095;
    for (int u0=0; u0<2; u0++) {
      int u = u0*256 + tid;
      int c = u >> 3, t8 = u & 7;
      *(bf16x8*)(args.out[2] + (size_t)(b*64+c)*4096 + n0 + t8*8) =
          *(const bf16x8*)&lT[c*PSTR + t8*8];
    }
  }
}

// ---- flash spatial attention, S^T form, no-max softmax, 6-way uneven K split ----
__global__ __launch_bounds__(256, 3) void attn_part(const short* __restrict__ qs,
    const short* __restrict__ ks, const short* __restrict__ vst,
    short* __restrict__ opart, float* __restrict__ ml) {
  __shared__ __align__(16) short sK[2][64*PSTR];
  __shared__ __align__(16) short sV[2][64*PSTR];
  __shared__ __align__(16) short sP[4][16*PSTR];
  const int tid = threadIdx.x;
  const int wave = tid>>6, lane = tid&63, quad = lane>>4, l16 = lane&15;
  const int qtile = blockIdx.x*2 + (wave>>1);
  const int qgo = (wave&1)*2;
  const int batch = blockIdx.y, kg = blockIdx.z;
  const int srow = tid >> 3, sc8 = tid & 7;
  const int ntile  = (kg < 4) ? 11 : 10;
  const int k0base = ((kg < 4) ? kg*11 : 44 + (kg-4)*10) * 64;

  const short* kb  = ks  + (size_t)batch*NTOK*64;
  const short* vtb = vst + (size_t)batch*64*NTOK;

  bf16x8 qa[2][2];
  for (int qg=0;qg<2;qg++) {
    const short* qp = qs + ((size_t)batch*NTOK + qtile*64 + (qgo+qg)*16 + l16)*64;
    qa[qg][0] = *(const bf16x8*)(qp + quad*8);
    qa[qg][1] = *(const bf16x8*)(qp + 32 + quad*8);
  }

  f32x4 ot[2][4];
  for (int qg=0;qg<2;qg++) for (int ct=0;ct<4;ct++) ot[qg][ct]=(f32x4){0.f,0.f,0.f,0.f};
  float lq[2] = {0.f,0.f};

  for (int h=0;h<2;h++) {
    int row = (h*256+tid)>>3, c8 = (h*256+tid)&7;
    *(bf16x8*)&sK[0][row*PSTR + c8*8] = *(const bf16x8*)(kb + (size_t)(k0base+row)*64 + c8*8);
    *(bf16x8*)&sV[0][row*PSTR + c8*8] = *(const bf16x8*)(vtb + (size_t)row*4096 + k0base + c8*8);
  }
  __syncthreads();

  for (int t=0; t<ntile; t++) {
    const int cur = t & 1;
    bf16x8 gk0, gk1, gv0, gv1;
    const bool pf = (t+1 < ntile);
    if (pf) {
      int k0 = k0base + (t+1)*64;
      gk0 = *(const bf16x8*)(kb + (size_t)(k0+srow)*64 + sc8*8);
      gv0 = *(const bf16x8*)(vtb + (size_t)srow*4096 + k0 + sc8*8);
      gk1 = *(const bf16x8*)(kb + (size_t)(k0+32+srow)*64 + sc8*8);
      gv1 = *(const bf16x8*)(vtb + (size_t)(32+srow)*4096 + k0 + sc8*8);
    }

    bf16x8 kf[4][2], vf[4][2];
    for (int mt=0;mt<4;mt++) {
      kf[mt][0] = *(const bf16x8*)&sK[cur][(mt*16+l16)*PSTR + quad*8];
      kf[mt][1] = *(const bf16x8*)&sK[cur][(mt*16+l16)*PSTR + 32 + quad*8];
      vf[mt][0] = *(const bf16x8*)&sV[cur][(mt*16+l16)*PSTR + quad*8];
      vf[mt][1] = *(const bf16x8*)&sV[cur][(mt*16+l16)*PSTR + 32 + quad*8];
    }

    for (int qg=0;qg<2;qg++) {
      f32x4 st[4];
      for (int mt=0;mt<4;mt++) {
        f32x4 z = {0.f,0.f,0.f,0.f};
        z = __builtin_amdgcn_mfma_f32_16x16x32_bf16(kf[mt][0], qa[qg][0], z, 0,0,0);
        z = __builtin_amdgcn_mfma_f32_16x16x32_bf16(kf[mt][1], qa[qg][1], z, 0,0,0);
        st[mt] = z;
      }
      float sum = 0.f;
      for (int mt=0;mt<4;mt++)
        for (int r=0;r<4;r++) {
          float p = __builtin_amdgcn_exp2f(st[mt][r]);
          st[mt][r] = p; sum += p;
        }
      lq[qg] += sum;
      short* lPw = sP[wave];
      for (int mt=0;mt<4;mt++) {
        bf16x4 pk;
        for (int r=0;r<4;r++) pk[r] = f2bf_t(st[mt][r]);
        *(bf16x4*)&lPw[l16*PSTR + mt*16 + quad*4] = pk;
      }
      bf16x8 pb0 = *(const bf16x8*)&lPw[l16*PSTR + quad*8];
      bf16x8 pb1 = *(const bf16x8*)&lPw[l16*PSTR + 32 + quad*8];
      for (int ct=0;ct<4;ct++) {
        ot[qg][ct] = __builtin_amdgcn_mfma_f32_16x16x32_bf16(vf[ct][0], pb0, ot[qg][ct], 0,0,0);
        ot[qg][ct] = __builtin_amdgcn_mfma_f32_16x16x32_bf16(vf[ct][1], pb1, ot[qg][ct], 0,0,0);
      }
    }

    if (pf) {
      int nxt = cur ^ 1;
      *(bf16x8*)&sK[nxt][srow*PSTR + sc8*8]      = gk0;
      *(bf16x8*)&sV[nxt][srow*PSTR + sc8*8]      = gv0;
      *(bf16x8*)&sK[nxt][(32+srow)*PSTR + sc8*8] = gk1;
      *(bf16x8*)&sV[nxt][(32+srow)*PSTR + sc8*8] = gv1;
    }
    __syncthreads();
  }

  size_t obase = (((size_t)batch*64 + qtile)*6 + kg) * 4096;
  for (int qg=0;qg<2;qg++)
    for (int ct=0;ct<4;ct++) {
      bf16x4 pk;
      for (int r=0;r<4;r++) pk[r] = f2bf(ot[qg][ct][r]);
      *(bf16x4*)&opart[obase + (size_t)((qgo+qg)*1024 + ct*256 + quad*64 + l16*4)] = pk;
    }
  float lt[2];
  for (int qg=0;qg<2;qg++) {
    float s = lq[qg];
    s += __shfl_xor(s, 16);
    s += __shfl_xor(s, 32);
    lt[qg] = s;
  }
  if (quad == 0) {
    float* mlp = ml + (((size_t)batch*64 + qtile)*6 + kg)*64;
    for (int qg=0;qg<2;qg++)
      mlp[(qgo+qg)*16 + l16] = lt[qg];
  }
}

// ---- channel QK^T, 64-way K split (qc pre-scaled -> G in log2 units) ----
__global__ __launch_bounds__(256) void chan_qk_part(const short* __restrict__ qc,
    const short* __restrict__ kc, float* __restrict__ Gpart) {
  const int tid = threadIdx.x;
  const int wave = tid>>6, lane = tid&63, quad = lane>>4, l16 = lane&15;
  const int ks_ = blockIdx.x, b = blockIdx.y;
  const int n0 = ks_*64;
  const short* qb = qc + (size_t)b*NTOK*64;
  const short* kb = kc + (size_t)b*NTOK*64;

  bf16x8 aq0 = *(const bf16x8*)(qb + (size_t)(wave*16+l16)*4096 + n0 + quad*8);
  bf16x8 aq1 = *(const bf16x8*)(qb + (size_t)(wave*16+l16)*4096 + n0 + 32 + quad*8);
  f32x4 acc[4];
  for (int nt=0;nt<4;nt++) {
    bf16x8 bk0 = *(const bf16x8*)(kb + (size_t)(nt*16+l16)*4096 + n0 + quad*8);
    bf16x8 bk1 = *(const bf16x8*)(kb + (size_t)(nt*16+l16)*4096 + n0 + 32 + quad*8);
    f32x4 z = {0.f,0.f,0.f,0.f};
    z = __builtin_amdgcn_mfma_f32_16x16x32_bf16(aq0, bk0, z, 0,0,0);
    z = __builtin_amdgcn_mfma_f32_16x16x32_bf16(aq1, bk1, z, 0,0,0);
    acc[nt] = z;
  }
  float* gp = Gpart + ((size_t)b*64 + ks_)*4096;
  for (int nt=0;nt<4;nt++)
    for (int r=0;r<4;r++)
      gp[(wave*16 + quad*4 + r)*64 + nt*16 + l16] = acc[nt][r];
}

// ---- reduce 64 partials + softmax over d (G already in log2 units) ----
__global__ __launch_bounds__(256) void chan_reduce_sm(const float* __restrict__ Gpart,
    float* __restrict__ att) {
  const int cg = blockIdx.x, b = blockIdx.y, t = threadIdx.x;
  const int c = cg*16 + (t>>4), dq = t & 15;
  const float* gp = Gpart + (size_t)b*64*4096 + c*64 + dq*4;
  f32x4 acc = {0.f,0.f,0.f,0.f};
  for (int ks_=0; ks_<64; ks_++)
    acc += *(const f32x4*)(gp + (size_t)ks_*4096);
  float mx = fmaxf(fmaxf(acc[0],acc[1]), fmaxf(acc[2],acc[3]));
  mx = fmaxf(mx, __shfl_xor(mx, 1));
  mx = fmaxf(mx, __shfl_xor(mx, 2));
  mx = fmaxf(mx, __shfl_xor(mx, 4));
  mx = fmaxf(mx, __shfl_xor(mx, 8));
  f32x4 p; float sum = 0.f;
  for (int j=0;j<4;j++){ p[j] = __builtin_amdgcn_exp2f(acc[j]-mx); sum += p[j]; }
  sum += __shfl_xor(sum, 1);
  sum += __shfl_xor(sum, 2);
  sum += __shfl_xor(sum, 4);
  sum += __shfl_xor(sum, 8);
  float inv = 1.f/sum;
  f32x4 r; for (int j=0;j<4;j++) r[j] = p[j]*inv;
  *(f32x4*)(att + (size_t)b*4096 + c*64 + dq*4) = r;
}

// ---- chan = att(64x64) . Vc(64x4096) via MFMA; grid (32 n-chunks, 4 b) ----
__global__ __launch_bounds__(256) void chan_av_mfma(const float* __restrict__ att,
    const short* __restrict__ vc, short* __restrict__ chan) {
  __shared__ __align__(16) short sVt[128*72];   // [n_local][d], stride 72
  const int tid = threadIdx.x;
  const int wave = tid>>6, lane = tid&63, quad = lane>>4, l16 = lane&15;
  const int b = blockIdx.y, n0 = blockIdx.x*128;
  const short* vb = vc + (size_t)b*NTOK*64;

  // stage Vc[d][n0..n0+127] -> sVt[n][d] (transposed)
  for (int it=0; it<4; it++) {
    int d = it*16 + (tid>>4);
    int nl8 = (tid&15)*8;
    bf16x8 gv = *(const bf16x8*)(vb + (size_t)d*4096 + n0 + nl8);
    for (int j=0;j<8;j++) sVt[(nl8+j)*72 + d] = gv[j];
  }
  // A-frags: att rows (f32 -> bf16)
  const float* ab = att + (size_t)b*4096;
  bf16x8 aq[4][2];
  for (int mt=0;mt<4;mt++)
    for (int kh=0;kh<2;kh++) {
      const float* ap = ab + (mt*16+l16)*64 + kh*32 + quad*8;
      f32x4 a0 = *(const f32x4*)ap, a1 = *(const f32x4*)(ap+4);
      for (int j=0;j<4;j++){ aq[mt][kh][j]=f2bf(a0[j]); aq[mt][kh][4+j]=f2bf(a1[j]); }
    }
  __syncthreads();

  short* cb = chan + (size_t)b*262144;
  for (int nt=0;nt<2;nt++) {
    int nl = wave*32 + nt*16 + l16;
    bf16x8 bv0 = *(const bf16x8*)&sVt[nl*72 + quad*8];
    bf16x8 bv1 = *(const bf16x8*)&sVt[nl*72 + 32 + quad*8];
    for (int mt=0;mt<4;mt++) {
      f32x4 acc = {0.f,0.f,0.f,0.f};
      acc = __builtin_amdgcn_mfma_f32_16x16x32_bf16(aq[mt][0], bv0, acc, 0,0,0);
      acc = __builtin_amdgcn_mfma_f32_16x16x32_bf16(aq[mt][1], bv1, acc, 0,0,0);
      for (int r=0;r<4;r++)
        cb[(size_t)(mt*16+quad*4+r)*4096 + n0 + nl] = f2bf(acc[r]);
    }
  }
}

// ---- sum 6 spatial partials + chan row + fusion: out = b*spat + a*chan + 2x ----
__global__ __launch_bounds__(256) void combine_fuse(const short* __restrict__ opart,
    const float* __restrict__ ml, const short* __restrict__ chan,
    const float* __restrict__ x, const float* __restrict__ pa,
    const float* __restrict__ pb, float* __restrict__ out) {
  __shared__ float sInv[64];
  const int qt = blockIdx.x, b = blockIdx.y, hz = blockIdx.z, t = threadIdx.x;
  const size_t base6 = ((size_t)b*64 + qt)*6;
  if (t < 64) {
    float den = 0.f;
    for (int kg=0;kg<6;kg++) den += ml[(base6+kg)*64 + t];
    sInv[t] = 1.f/den;
  }
  __syncthreads();

  const int e0 = hz*2048 + t*8;
  const int q = e0 >> 6;
  const int qg = q >> 4, l16 = q & 15;
  const int seg = (t&7) >> 1, quad0 = (t&1)*2;

  float accS[8];
  for (int j=0;j<8;j++) accS[j]=0.f;
  for (int kg=0;kg<6;kg++) {
    const short* op = opart + (base6+kg)*4096 + qg*1024 + seg*256 + l16*4;
    bf16x4 c0 = *(const bf16x4*)(op + quad0*64);
    bf16x4 c1 = *(const bf16x4*)(op + (quad0+1)*64);
    for (int r=0;r<4;r++) { accS[r] += bf2f(c0[r]); accS[4+r] += bf2f(c1[r]); }
  }
  float inv = sInv[q];
  bf16x8 cv = *(const bf16x8*)(chan + (size_t)b*262144 + qt*4096 + e0);
  const float av = pa[0], bv = pb[0];
  size_t flat = ((size_t)b*64 + qt)*4096 + e0;
  f32x4 x0 = *(const f32x4*)(x + flat);
  f32x4 x1 = *(const f32x4*)(x + flat + 4);
  f32x4 r0, r1;
  for (int j=0;j<4;j++) {
    r0[j] = bv*accS[j]*inv   + av*bf2f(cv[j])   + 2.f*x0[j];
    r1[j] = bv*accS[4+j]*inv + av*bf2f(cv[4+j]) + 2.f*x1[j];
  }
  *(f32x4*)(out + flat)     = r0;
  *(f32x4*)(out + flat + 4) = r1;
}

extern "C" void kernel_launch(void* const* d_in, const int* in_sizes, int n_in,
                              void* d_out, int out_size, void* d_ws, size_t ws_size,
                              hipStream_t stream) {
  const float* x = (const float*)d_in[0];
  char* ws = (char*)d_ws;
  const size_t MB = 1048576;
  short* qs    = (short*)(ws + 0*MB);
  short* ks_   = (short*)(ws + 2*MB);
  short* vst   = (short*)(ws + 4*MB);
  short* qc    = (short*)(ws + 6*MB);
  short* kc    = (short*)(ws + 8*MB);
  short* vc    = (short*)(ws + 10*MB);
  short* opart = (short*)(ws + 12*MB);   // 12 MB (6 kg)
  float* ml    = (float*)(ws + 24*MB);   // 384 KB
  short* wt    = (short*)(ws + 25*MB);   // 48 KB
  float* att   = (float*)(ws + 25*MB + 524288);  // 64 KB
  short* chan  = (short*)(ws + 26*MB);   // 2 MB
  float* Gpart = (float*)(ws + 0*MB);    // overlays qs/ks (dead after attn_part)

  PrepArgs pa;
  ConvArgs ca;
  ca.x = x; ca.wt = wt;
  for (int i=0;i<6;i++) {
    pa.w[i]    = (const float*)d_in[1+2*i];
    ca.bias[i] = (const float*)d_in[2+2*i];
  }
  pa.wt = wt;
  ca.out[0]=qs; ca.out[1]=ks_; ca.out[2]=vst;
  ca.out[3]=qc; ca.out[4]=kc; ca.out[5]=vc;

  hipLaunchKernelGGL(prep_w, dim3(6), dim3(256), 0, stream, pa);
  hipLaunchKernelGGL(conv_qkv, dim3(256,2), dim3(256), 0, stream, ca);
  hipLaunchKernelGGL(attn_part, dim3(32,4,6), dim3(256), 0, stream, qs, ks_, vst, opart, ml);
  hipLaunchKernelGGL(chan_qk_part, dim3(64,4), dim3(256), 0, stream, qc, kc, Gpart);
  hipLaunchKernelGGL(chan_reduce_sm, dim3(4,4), dim3(256), 0, stream, Gpart, att);
  hipLaunchKernelGGL(chan_av_mfma, dim3(32,4), dim3(256), 0, stream, att, vc, chan);
  hipLaunchKernelGGL(combine_fuse, dim3(64,4,2), dim3(256), 0, stream,
                     opart, ml, chan, x, (const float*)d_in[13], (const float*)d_in[14],
                     (float*)d_out);
}

// Round 10
// 135.577 us; speedup vs baseline: 1.0654x; 1.0654x over previous
//
#include <hip/hip_runtime.h>

#define NTOK 4096   // H*W
#define PSTR 72     // padded LDS row stride (shorts)

typedef short bf16x8 __attribute__((ext_vector_type(8)));
typedef short bf16x4 __attribute__((ext_vector_type(4)));
typedef float f32x4 __attribute__((ext_vector_type(4)));

__device__ __forceinline__ short f2bf(float f) {          // RNE
  union { float f; unsigned u; } v; v.f = f;
  unsigned r = v.u + 0x7fffu + ((v.u >> 16) & 1u);
  return (short)(r >> 16);
}
__device__ __forceinline__ short f2bf_t(float f) {        // truncate (P matrix only)
  union { float f; unsigned u; } v; v.f = f;
  return (short)(v.u >> 16);
}
__device__ __forceinline__ float bf2f(short s) {
  union { unsigned u; float f; } v; v.u = ((unsigned)(unsigned short)s) << 16;
  return v.f;
}

struct ConvArgs {
  const float* x;
  const float* w[6];
  const float* bias[6];
  short* out[6];   // out[0]=qs, out[3]=qc (both pre-scaled); out[2]=vs_t (channel-major)
};

#define QSC (0.125f * 1.44269504088896f)

// ---- fused 1x1 conv: y = x @ W + b -> bf16; grid (256 token-tiles, 2 wi-halves).
// Weights staged f32 -> bf16 W^T in LDS per block (R1-R4 verified pattern; weights
// are 96 KB total -> L2-hot). Removes the separate prep_w launch.
__global__ __launch_bounds__(256) void conv_qkv(ConvArgs args) {
  __shared__ __align__(16) short lWt[3][64*PSTR];   // this half's 3 W^T matrices
  __shared__ __align__(16) short lT[64*PSTR];       // transpose buf for vs_t (half 0)
  const int tid = threadIdx.x;
  const int wave = tid >> 6, lane = tid & 63;
  const int quad = lane >> 4, l16 = lane & 15;
  const int half = blockIdx.y;

  // stage W^T (d-major) for wi = half*3 .. half*3+2; scale wq_s / wq_c by QSC
  for (int j = 0; j < 3; j++) {
    const int wi = half*3 + j;
    const float* w = args.w[wi];
    const float sc = (wi == 0 || wi == 3) ? QSC : 1.f;
    const f32x4* wsrc = (const f32x4*)w;
    for (int u0 = 0; u0 < 4; u0++) {
      int u = u0 * 256 + tid;           // float4 unit: c = u>>4, d-quad = u&15
      int c = u >> 4, d4 = u & 15;
      f32x4 v = wsrc[u];
      for (int k = 0; k < 4; k++)
        lWt[j][(d4*4+k)*PSTR + c] = f2bf(v[k]*sc);
    }
  }

  int row = blockIdx.x * 64 + wave*16 + l16;
  const float* xr = args.x + (size_t)row*64 + quad*8;
  f32x4 x0 = *(const f32x4*)xr;
  f32x4 x1 = *(const f32x4*)(xr+4);
  f32x4 x2 = *(const f32x4*)(xr+32);
  f32x4 x3 = *(const f32x4*)(xr+36);
  bf16x8 a0, a1;
  for (int j=0;j<4;j++){ a0[j]=f2bf(x0[j]); a0[4+j]=f2bf(x1[j]); a1[j]=f2bf(x2[j]); a1[4+j]=f2bf(x3[j]); }
  __syncthreads();

  int orow_base = blockIdx.x*64 + wave*16 + quad*4;
  for (int j=0; j<3; j++) {
    const int wi = half*3 + j;
    for (int dt=0; dt<4; dt++) {
      bf16x8 b0 = *(const bf16x8*)&lWt[j][(dt*16+l16)*PSTR + quad*8];
      bf16x8 b1 = *(const bf16x8*)&lWt[j][(dt*16+l16)*PSTR + 32 + quad*8];
      f32x4 acc = {0.f,0.f,0.f,0.f};
      acc = __builtin_amdgcn_mfma_f32_16x16x32_bf16(a0, b0, acc, 0,0,0);
      acc = __builtin_amdgcn_mfma_f32_16x16x32_bf16(a1, b1, acc, 0,0,0);
      float bias = args.bias[wi][dt*16+l16];
      if (wi == 0 || wi == 3) bias *= QSC;
      if (wi != 2) {
        short* outp = args.out[wi];
        for (int r=0;r<4;r++)
          outp[(size_t)(orow_base + r)*64 + dt*16 + l16] = f2bf(acc[r] + bias);
      } else {
        for (int r=0;r<4;r++)
          lT[(dt*16+l16)*PSTR + wave*16 + quad*4 + r] = f2bf(acc[r] + bias);
      }
    }
  }
  if (half == 0) {
    __syncthreads();
    int b  = (blockIdx.x*64) >> 12;
    int n0 = (blockIdx.x*64) & 4095;
    for (int u0=0; u0<2; u0++) {
      int u = u0*256 + tid;
      int c = u >> 3, t8 = u & 7;
      *(bf16x8*)(args.out[2] + (size_t)(b*64+c)*4096 + n0 + t8*8) =
          *(const bf16x8*)&lT[c*PSTR + t8*8];
    }
  }
}

// ---- flash spatial attention, S^T form, no-max softmax, 6-way uneven K split ----
__global__ __launch_bounds__(256, 3) void attn_part(const short* __restrict__ qs,
    const short* __restrict__ ks, const short* __restrict__ vst,
    short* __restrict__ opart, float* __restrict__ ml) {
  __shared__ __align__(16) short sK[2][64*PSTR];
  __shared__ __align__(16) short sV[2][64*PSTR];
  __shared__ __align__(16) short sP[4][16*PSTR];
  const int tid = threadIdx.x;
  const int wave = tid>>6, lane = tid&63, quad = lane>>4, l16 = lane&15;
  const int qtile = blockIdx.x*2 + (wave>>1);
  const int qgo = (wave&1)*2;
  const int batch = blockIdx.y, kg = blockIdx.z;
  const int srow = tid >> 3, sc8 = tid & 7;
  const int ntile  = (kg < 4) ? 11 : 10;
  const int k0base = ((kg < 4) ? kg*11 : 44 + (kg-4)*10) * 64;

  const short* kb  = ks  + (size_t)batch*NTOK*64;
  const short* vtb = vst + (size_t)batch*64*NTOK;

  bf16x8 qa[2][2];
  for (int qg=0;qg<2;qg++) {
    const short* qp = qs + ((size_t)batch*NTOK + qtile*64 + (qgo+qg)*16 + l16)*64;
    qa[qg][0] = *(const bf16x8*)(qp + quad*8);
    qa[qg][1] = *(const bf16x8*)(qp + 32 + quad*8);
  }

  f32x4 ot[2][4];
  for (int qg=0;qg<2;qg++) for (int ct=0;ct<4;ct++) ot[qg][ct]=(f32x4){0.f,0.f,0.f,0.f};
  float lq[2] = {0.f,0.f};

  for (int h=0;h<2;h++) {
    int row = (h*256+tid)>>3, c8 = (h*256+tid)&7;
    *(bf16x8*)&sK[0][row*PSTR + c8*8] = *(const bf16x8*)(kb + (size_t)(k0base+row)*64 + c8*8);
    *(bf16x8*)&sV[0][row*PSTR + c8*8] = *(const bf16x8*)(vtb + (size_t)row*4096 + k0base + c8*8);
  }
  __syncthreads();

  for (int t=0; t<ntile; t++) {
    const int cur = t & 1;
    bf16x8 gk0, gk1, gv0, gv1;
    const bool pf = (t+1 < ntile);
    if (pf) {
      int k0 = k0base + (t+1)*64;
      gk0 = *(const bf16x8*)(kb + (size_t)(k0+srow)*64 + sc8*8);
      gv0 = *(const bf16x8*)(vtb + (size_t)srow*4096 + k0 + sc8*8);
      gk1 = *(const bf16x8*)(kb + (size_t)(k0+32+srow)*64 + sc8*8);
      gv1 = *(const bf16x8*)(vtb + (size_t)(32+srow)*4096 + k0 + sc8*8);
    }

    bf16x8 kf[4][2], vf[4][2];
    for (int mt=0;mt<4;mt++) {
      kf[mt][0] = *(const bf16x8*)&sK[cur][(mt*16+l16)*PSTR + quad*8];
      kf[mt][1] = *(const bf16x8*)&sK[cur][(mt*16+l16)*PSTR + 32 + quad*8];
      vf[mt][0] = *(const bf16x8*)&sV[cur][(mt*16+l16)*PSTR + quad*8];
      vf[mt][1] = *(const bf16x8*)&sV[cur][(mt*16+l16)*PSTR + 32 + quad*8];
    }

    for (int qg=0;qg<2;qg++) {
      f32x4 st[4];
      for (int mt=0;mt<4;mt++) {
        f32x4 z = {0.f,0.f,0.f,0.f};
        z = __builtin_amdgcn_mfma_f32_16x16x32_bf16(kf[mt][0], qa[qg][0], z, 0,0,0);
        z = __builtin_amdgcn_mfma_f32_16x16x32_bf16(kf[mt][1], qa[qg][1], z, 0,0,0);
        st[mt] = z;
      }
      float sum = 0.f;
      for (int mt=0;mt<4;mt++)
        for (int r=0;r<4;r++) {
          float p = __builtin_amdgcn_exp2f(st[mt][r]);
          st[mt][r] = p; sum += p;
        }
      lq[qg] += sum;
      short* lPw = sP[wave];
      for (int mt=0;mt<4;mt++) {
        bf16x4 pk;
        for (int r=0;r<4;r++) pk[r] = f2bf_t(st[mt][r]);
        *(bf16x4*)&lPw[l16*PSTR + mt*16 + quad*4] = pk;
      }
      bf16x8 pb0 = *(const bf16x8*)&lPw[l16*PSTR + quad*8];
      bf16x8 pb1 = *(const bf16x8*)&lPw[l16*PSTR + 32 + quad*8];
      for (int ct=0;ct<4;ct++) {
        ot[qg][ct] = __builtin_amdgcn_mfma_f32_16x16x32_bf16(vf[ct][0], pb0, ot[qg][ct], 0,0,0);
        ot[qg][ct] = __builtin_amdgcn_mfma_f32_16x16x32_bf16(vf[ct][1], pb1, ot[qg][ct], 0,0,0);
      }
    }

    if (pf) {
      int nxt = cur ^ 1;
      *(bf16x8*)&sK[nxt][srow*PSTR + sc8*8]      = gk0;
      *(bf16x8*)&sV[nxt][srow*PSTR + sc8*8]      = gv0;
      *(bf16x8*)&sK[nxt][(32+srow)*PSTR + sc8*8] = gk1;
      *(bf16x8*)&sV[nxt][(32+srow)*PSTR + sc8*8] = gv1;
    }
    __syncthreads();
  }

  size_t obase = (((size_t)batch*64 + qtile)*6 + kg) * 4096;
  for (int qg=0;qg<2;qg++)
    for (int ct=0;ct<4;ct++) {
      bf16x4 pk;
      for (int r=0;r<4;r++) pk[r] = f2bf(ot[qg][ct][r]);
      *(bf16x4*)&opart[obase + (size_t)((qgo+qg)*1024 + ct*256 + quad*64 + l16*4)] = pk;
    }
  float lt[2];
  for (int qg=0;qg<2;qg++) {
    float s = lq[qg];
    s += __shfl_xor(s, 16);
    s += __shfl_xor(s, 32);
    lt[qg] = s;
  }
  if (quad == 0) {
    float* mlp = ml + (((size_t)batch*64 + qtile)*6 + kg)*64;
    for (int qg=0;qg<2;qg++)
      mlp[(qgo+qg)*16 + l16] = lt[qg];
  }
}

// ---- channel QK^T, 64-way K split (qc pre-scaled -> G in log2 units) ----
__global__ __launch_bounds__(256) void chan_qk_part(const short* __restrict__ qc,
    const short* __restrict__ kc, float* __restrict__ Gpart) {
  const int tid = threadIdx.x;
  const int wave = tid>>6, lane = tid&63, quad = lane>>4, l16 = lane&15;
  const int ks_ = blockIdx.x, b = blockIdx.y;
  const int n0 = ks_*64;
  const short* qb = qc + (size_t)b*NTOK*64;
  const short* kb = kc + (size_t)b*NTOK*64;

  bf16x8 aq0 = *(const bf16x8*)(qb + (size_t)(wave*16+l16)*4096 + n0 + quad*8);
  bf16x8 aq1 = *(const bf16x8*)(qb + (size_t)(wave*16+l16)*4096 + n0 + 32 + quad*8);
  f32x4 acc[4];
  for (int nt=0;nt<4;nt++) {
    bf16x8 bk0 = *(const bf16x8*)(kb + (size_t)(nt*16+l16)*4096 + n0 + quad*8);
    bf16x8 bk1 = *(const bf16x8*)(kb + (size_t)(nt*16+l16)*4096 + n0 + 32 + quad*8);
    f32x4 z = {0.f,0.f,0.f,0.f};
    z = __builtin_amdgcn_mfma_f32_16x16x32_bf16(aq0, bk0, z, 0,0,0);
    z = __builtin_amdgcn_mfma_f32_16x16x32_bf16(aq1, bk1, z, 0,0,0);
    acc[nt] = z;
  }
  float* gp = Gpart + ((size_t)b*64 + ks_)*4096;
  for (int nt=0;nt<4;nt++)
    for (int r=0;r<4;r++)
      gp[(wave*16 + quad*4 + r)*64 + nt*16 + l16] = acc[nt][r];
}

// ---- sum 6 spatial partials + (chan G-reduce + softmax + AV row) + fusion ----
// grid (64 qt, 4 b, 2 half), block 256. Wave 0 prologue computes att row qt.
__global__ __launch_bounds__(256) void combine_fuse(const short* __restrict__ opart,
    const float* __restrict__ ml, const float* __restrict__ Gpart,
    const short* __restrict__ vc, const float* __restrict__ x,
    const float* __restrict__ pa, const float* __restrict__ pb,
    float* __restrict__ out) {
  __shared__ float sInv[64];
  __shared__ float sAtt[64];
  const int qt = blockIdx.x, b = blockIdx.y, hz = blockIdx.z, t = threadIdx.x;
  const size_t base6 = ((size_t)b*64 + qt)*6;
  if (t < 64) {
    float den = 0.f;
    for (int kg=0;kg<6;kg++) den += ml[(base6+kg)*64 + t];
    sInv[t] = 1.f/den;
    // channel attention row qt: reduce 64 Gpart chunks, wave softmax over d
    float g = 0.f;
    const float* gp = Gpart + (size_t)b*64*4096 + qt*64 + t;
    for (int ks=0; ks<64; ks++) g += gp[(size_t)ks*4096];
    float m = g;
    for (int off=1; off<64; off<<=1) m = fmaxf(m, __shfl_xor(m, off));
    float p = __builtin_amdgcn_exp2f(g - m);
    float s = p;
    for (int off=1; off<64; off<<=1) s += __shfl_xor(s, off);
    sAtt[t] = p/s;
  }
  __syncthreads();

  const int e0 = hz*2048 + t*8;           // 8 consecutive output elems
  const int q = e0 >> 6;
  const int qg = q >> 4, l16 = q & 15;
  const int seg = (t&7) >> 1, quad0 = (t&1)*2;

  float accS[8];
  for (int j=0;j<8;j++) accS[j]=0.f;
  for (int kg=0;kg<6;kg++) {
    const short* op = opart + (base6+kg)*4096 + qg*1024 + seg*256 + l16*4;
    bf16x4 c0 = *(const bf16x4*)(op + quad0*64);
    bf16x4 c1 = *(const bf16x4*)(op + (quad0+1)*64);
    for (int r=0;r<4;r++) { accS[r] += bf2f(c0[r]); accS[4+r] += bf2f(c1[r]); }
  }
  float inv = sInv[q];
  float accC[8];
  for (int j=0;j<8;j++) accC[j]=0.f;
  const short* vb = vc + (size_t)b*NTOK*64;
  for (int d=0; d<64; d++) {
    bf16x8 v = *(const bf16x8*)(vb + (size_t)d*4096 + e0);
    float a = sAtt[d];
    for (int j=0;j<8;j++) accC[j] += a*bf2f(v[j]);
  }
  const float av = pa[0], bv = pb[0];
  size_t flat = ((size_t)b*64 + qt)*4096 + e0;
  f32x4 x0 = *(const f32x4*)(x + flat);
  f32x4 x1 = *(const f32x4*)(x + flat + 4);
  f32x4 r0, r1;
  for (int j=0;j<4;j++) {
    r0[j] = bv*accS[j]*inv   + av*accC[j]   + 2.f*x0[j];
    r1[j] = bv*accS[4+j]*inv + av*accC[4+j] + 2.f*x1[j];
  }
  *(f32x4*)(out + flat)     = r0;
  *(f32x4*)(out + flat + 4) = r1;
}

extern "C" void kernel_launch(void* const* d_in, const int* in_sizes, int n_in,
                              void* d_out, int out_size, void* d_ws, size_t ws_size,
                              hipStream_t stream) {
  const float* x = (const float*)d_in[0];
  char* ws = (char*)d_ws;
  const size_t MB = 1048576;
  short* qs    = (short*)(ws + 0*MB);
  short* ks_   = (short*)(ws + 2*MB);
  short* vst   = (short*)(ws + 4*MB);
  short* qc    = (short*)(ws + 6*MB);
  short* kc    = (short*)(ws + 8*MB);
  short* vc    = (short*)(ws + 10*MB);
  short* opart = (short*)(ws + 12*MB);   // 12 MB (6 kg)
  float* ml    = (float*)(ws + 24*MB);   // 384 KB
  float* Gpart = (float*)(ws + 0*MB);    // overlays qs/ks (dead after attn_part)

  ConvArgs ca;
  ca.x = x;
  for (int i=0;i<6;i++) {
    ca.w[i]    = (const float*)d_in[1+2*i];
    ca.bias[i] = (const float*)d_in[2+2*i];
  }
  ca.out[0]=qs; ca.out[1]=ks_; ca.out[2]=vst;
  ca.out[3]=qc; ca.out[4]=kc; ca.out[5]=vc;

  hipLaunchKernelGGL(conv_qkv, dim3(256,2), dim3(256), 0, stream, ca);
  hipLaunchKernelGGL(attn_part, dim3(32,4,6), dim3(256), 0, stream, qs, ks_, vst, opart, ml);
  hipLaunchKernelGGL(chan_qk_part, dim3(64,4), dim3(256), 0, stream, qc, kc, Gpart);
  hipLaunchKernelGGL(combine_fuse, dim3(64,4,2), dim3(256), 0, stream,
                     opart, ml, Gpart, vc, x, (const float*)d_in[13], (const float*)d_in[14],
                     (float*)d_out);
}

// Round 11
// 133.394 us; speedup vs baseline: 1.0829x; 1.0164x over previous
//
#include <hip/hip_runtime.h>

#define NTOK 4096   // H*W
#define PSTR 72     // padded LDS row stride (shorts)

#if defined(__has_builtin)
#if __has_builtin(__builtin_amdgcn_mfma_f32_16x16x16bf16_1k)
#define HAVE_MFMA16 1
#endif
#endif

typedef short bf16x8 __attribute__((ext_vector_type(8)));
typedef short bf16x4 __attribute__((ext_vector_type(4)));
typedef float f32x4 __attribute__((ext_vector_type(4)));

__device__ __forceinline__ short f2bf(float f) {          // RNE
  union { float f; unsigned u; } v; v.f = f;
  unsigned r = v.u + 0x7fffu + ((v.u >> 16) & 1u);
  return (short)(r >> 16);
}
__device__ __forceinline__ short f2bf_t(float f) {        // truncate (P matrix only)
  union { float f; unsigned u; } v; v.f = f;
  return (short)(v.u >> 16);
}
__device__ __forceinline__ float bf2f(short s) {
  union { unsigned u; float f; } v; v.u = ((unsigned)(unsigned short)s) << 16;
  return v.f;
}

struct ConvArgs {
  const float* x;
  const float* w[6];
  const float* bias[6];
  short* out[6];   // out[0]=qs, out[3]=qc (both pre-scaled); out[2]=vs_t (channel-major)
};

#define QSC (0.125f * 1.44269504088896f)

// ---- fused 1x1 conv: y = x @ W + b -> bf16; grid (256 token-tiles, 2 wi-halves) ----
__global__ __launch_bounds__(256) void conv_qkv(ConvArgs args) {
  __shared__ __align__(16) short lWt[3][64*PSTR];   // this half's 3 W^T matrices
  __shared__ __align__(16) short lT[64*PSTR];       // transpose buf for vs_t (half 0)
  const int tid = threadIdx.x;
  const int wave = tid >> 6, lane = tid & 63;
  const int quad = lane >> 4, l16 = lane & 15;
  const int half = blockIdx.y;

  for (int j = 0; j < 3; j++) {
    const int wi = half*3 + j;
    const float* w = args.w[wi];
    const float sc = (wi == 0 || wi == 3) ? QSC : 1.f;
    const f32x4* wsrc = (const f32x4*)w;
    for (int u0 = 0; u0 < 4; u0++) {
      int u = u0 * 256 + tid;
      int c = u >> 4, d4 = u & 15;
      f32x4 v = wsrc[u];
      for (int k = 0; k < 4; k++)
        lWt[j][(d4*4+k)*PSTR + c] = f2bf(v[k]*sc);
    }
  }

  int row = blockIdx.x * 64 + wave*16 + l16;
  const float* xr = args.x + (size_t)row*64 + quad*8;
  f32x4 x0 = *(const f32x4*)xr;
  f32x4 x1 = *(const f32x4*)(xr+4);
  f32x4 x2 = *(const f32x4*)(xr+32);
  f32x4 x3 = *(const f32x4*)(xr+36);
  bf16x8 a0, a1;
  for (int j=0;j<4;j++){ a0[j]=f2bf(x0[j]); a0[4+j]=f2bf(x1[j]); a1[j]=f2bf(x2[j]); a1[4+j]=f2bf(x3[j]); }
  __syncthreads();

  int orow_base = blockIdx.x*64 + wave*16 + quad*4;
  for (int j=0; j<3; j++) {
    const int wi = half*3 + j;
    for (int dt=0; dt<4; dt++) {
      bf16x8 b0 = *(const bf16x8*)&lWt[j][(dt*16+l16)*PSTR + quad*8];
      bf16x8 b1 = *(const bf16x8*)&lWt[j][(dt*16+l16)*PSTR + 32 + quad*8];
      f32x4 acc = {0.f,0.f,0.f,0.f};
      acc = __builtin_amdgcn_mfma_f32_16x16x32_bf16(a0, b0, acc, 0,0,0);
      acc = __builtin_amdgcn_mfma_f32_16x16x32_bf16(a1, b1, acc, 0,0,0);
      float bias = args.bias[wi][dt*16+l16];
      if (wi == 0 || wi == 3) bias *= QSC;
      if (wi != 2) {
        short* outp = args.out[wi];
        for (int r=0;r<4;r++)
          outp[(size_t)(orow_base + r)*64 + dt*16 + l16] = f2bf(acc[r] + bias);
      } else {
        for (int r=0;r<4;r++)
          lT[(dt*16+l16)*PSTR + wave*16 + quad*4 + r] = f2bf(acc[r] + bias);
      }
    }
  }
  if (half == 0) {
    __syncthreads();
    int b  = (blockIdx.x*64) >> 12;
    int n0 = (blockIdx.x*64) & 4095;
    for (int u0=0; u0<2; u0++) {
      int u = u0*256 + tid;
      int c = u >> 3, t8 = u & 7;
      *(bf16x8*)(args.out[2] + (size_t)(b*64+c)*4096 + n0 + t8*8) =
          *(const bf16x8*)&lT[c*PSTR + t8*8];
    }
  }
}

// ---- flash spatial attention, S^T form, no-max softmax, 6-way uneven K split.
// PV uses K=16 MFMA whose B-layout == QK's C/D layout -> P stays in registers
// (no LDS round-trip RAW chain). Fallback (no builtin): R10's LDS P path. ----
__global__ __launch_bounds__(256, 3) void attn_part(const short* __restrict__ qs,
    const short* __restrict__ ks, const short* __restrict__ vst,
    short* __restrict__ opart, float* __restrict__ ml) {
  __shared__ __align__(16) short sK[2][64*PSTR];
  __shared__ __align__(16) short sV[2][64*PSTR];
#ifndef HAVE_MFMA16
  __shared__ __align__(16) short sP[4][16*PSTR];
#endif
  const int tid = threadIdx.x;
  const int wave = tid>>6, lane = tid&63, quad = lane>>4, l16 = lane&15;
  const int qtile = blockIdx.x*2 + (wave>>1);
  const int qgo = (wave&1)*2;
  const int batch = blockIdx.y, kg = blockIdx.z;
  const int srow = tid >> 3, sc8 = tid & 7;
  const int ntile  = (kg < 4) ? 11 : 10;
  const int k0base = ((kg < 4) ? kg*11 : 44 + (kg-4)*10) * 64;

  const short* kb  = ks  + (size_t)batch*NTOK*64;
  const short* vtb = vst + (size_t)batch*64*NTOK;

  bf16x8 qa[2][2];
  for (int qg=0;qg<2;qg++) {
    const short* qp = qs + ((size_t)batch*NTOK + qtile*64 + (qgo+qg)*16 + l16)*64;
    qa[qg][0] = *(const bf16x8*)(qp + quad*8);
    qa[qg][1] = *(const bf16x8*)(qp + 32 + quad*8);
  }

  f32x4 ot[2][4];
  for (int qg=0;qg<2;qg++) for (int ct=0;ct<4;ct++) ot[qg][ct]=(f32x4){0.f,0.f,0.f,0.f};
  float lq[2] = {0.f,0.f};

  for (int h=0;h<2;h++) {
    int row = (h*256+tid)>>3, c8 = (h*256+tid)&7;
    *(bf16x8*)&sK[0][row*PSTR + c8*8] = *(const bf16x8*)(kb + (size_t)(k0base+row)*64 + c8*8);
    *(bf16x8*)&sV[0][row*PSTR + c8*8] = *(const bf16x8*)(vtb + (size_t)row*4096 + k0base + c8*8);
  }
  __syncthreads();

  for (int t=0; t<ntile; t++) {
    const int cur = t & 1;
    bf16x8 gk0, gk1, gv0, gv1;
    const bool pf = (t+1 < ntile);
    if (pf) {
      int k0 = k0base + (t+1)*64;
      gk0 = *(const bf16x8*)(kb + (size_t)(k0+srow)*64 + sc8*8);
      gv0 = *(const bf16x8*)(vtb + (size_t)srow*4096 + k0 + sc8*8);
      gk1 = *(const bf16x8*)(kb + (size_t)(k0+32+srow)*64 + sc8*8);
      gv1 = *(const bf16x8*)(vtb + (size_t)(32+srow)*4096 + k0 + sc8*8);
    }

    bf16x8 kf[4][2];
    for (int mt=0;mt<4;mt++) {
      kf[mt][0] = *(const bf16x8*)&sK[cur][(mt*16+l16)*PSTR + quad*8];
      kf[mt][1] = *(const bf16x8*)&sK[cur][(mt*16+l16)*PSTR + 32 + quad*8];
    }
#ifdef HAVE_MFMA16
    // K=16 A-frags of V^T: A[m=ch l16][k=quad*4+j], key block mt
    bf16x4 vf16[4][4];
    for (int ct=0;ct<4;ct++)
      for (int mt=0;mt<4;mt++)
        vf16[ct][mt] = *(const bf16x4*)&sV[cur][(ct*16+l16)*PSTR + mt*16 + quad*4];
#else
    bf16x8 vf[4][2];
    for (int mt=0;mt<4;mt++) {
      vf[mt][0] = *(const bf16x8*)&sV[cur][(mt*16+l16)*PSTR + quad*8];
      vf[mt][1] = *(const bf16x8*)&sV[cur][(mt*16+l16)*PSTR + 32 + quad*8];
    }
#endif

    for (int qg=0;qg<2;qg++) {
      f32x4 st[4];
      for (int mt=0;mt<4;mt++) {
        f32x4 z = {0.f,0.f,0.f,0.f};
        z = __builtin_amdgcn_mfma_f32_16x16x32_bf16(kf[mt][0], qa[qg][0], z, 0,0,0);
        z = __builtin_amdgcn_mfma_f32_16x16x32_bf16(kf[mt][1], qa[qg][1], z, 0,0,0);
        st[mt] = z;
      }
      float sum = 0.f;
      for (int mt=0;mt<4;mt++)
        for (int r=0;r<4;r++) {
          float p = __builtin_amdgcn_exp2f(st[mt][r]);
          st[mt][r] = p; sum += p;
        }
      lq[qg] += sum;
#ifdef HAVE_MFMA16
      // P^T C/D layout (col=l16=query, row=quad*4+r=key) IS the K=16 B-operand
      // layout B[n=l16][k=quad*4+r] -> feed MFMA directly from registers.
      bf16x4 pk[4];
      for (int mt=0;mt<4;mt++)
        for (int r=0;r<4;r++) pk[mt][r] = f2bf_t(st[mt][r]);
      for (int ct=0;ct<4;ct++)
        for (int mt=0;mt<4;mt++)
          ot[qg][ct] = __builtin_amdgcn_mfma_f32_16x16x16bf16_1k(
              vf16[ct][mt], pk[mt], ot[qg][ct], 0,0,0);
#else
      short* lPw = sP[wave];
      for (int mt=0;mt<4;mt++) {
        bf16x4 pk;
        for (int r=0;r<4;r++) pk[r] = f2bf_t(st[mt][r]);
        *(bf16x4*)&lPw[l16*PSTR + mt*16 + quad*4] = pk;
      }
      bf16x8 pb0 = *(const bf16x8*)&lPw[l16*PSTR + quad*8];
      bf16x8 pb1 = *(const bf16x8*)&lPw[l16*PSTR + 32 + quad*8];
      for (int ct=0;ct<4;ct++) {
        ot[qg][ct] = __builtin_amdgcn_mfma_f32_16x16x32_bf16(vf[ct][0], pb0, ot[qg][ct], 0,0,0);
        ot[qg][ct] = __builtin_amdgcn_mfma_f32_16x16x32_bf16(vf[ct][1], pb1, ot[qg][ct], 0,0,0);
      }
#endif
    }

    if (pf) {
      int nxt = cur ^ 1;
      *(bf16x8*)&sK[nxt][srow*PSTR + sc8*8]      = gk0;
      *(bf16x8*)&sV[nxt][srow*PSTR + sc8*8]      = gv0;
      *(bf16x8*)&sK[nxt][(32+srow)*PSTR + sc8*8] = gk1;
      *(bf16x8*)&sV[nxt][(32+srow)*PSTR + sc8*8] = gv1;
    }
    __syncthreads();
  }

  size_t obase = (((size_t)batch*64 + qtile)*6 + kg) * 4096;
  for (int qg=0;qg<2;qg++)
    for (int ct=0;ct<4;ct++) {
      bf16x4 pk;
      for (int r=0;r<4;r++) pk[r] = f2bf(ot[qg][ct][r]);
      *(bf16x4*)&opart[obase + (size_t)((qgo+qg)*1024 + ct*256 + quad*64 + l16*4)] = pk;
    }
  float lt[2];
  for (int qg=0;qg<2;qg++) {
    float s = lq[qg];
    s += __shfl_xor(s, 16);
    s += __shfl_xor(s, 32);
    lt[qg] = s;
  }
  if (quad == 0) {
    float* mlp = ml + (((size_t)batch*64 + qtile)*6 + kg)*64;
    for (int qg=0;qg<2;qg++)
      mlp[(qgo+qg)*16 + l16] = lt[qg];
  }
}

// ---- channel QK^T, 64-way K split (qc pre-scaled -> G in log2 units) ----
__global__ __launch_bounds__(256) void chan_qk_part(const short* __restrict__ qc,
    const short* __restrict__ kc, float* __restrict__ Gpart) {
  const int tid = threadIdx.x;
  const int wave = tid>>6, lane = tid&63, quad = lane>>4, l16 = lane&15;
  const int ks_ = blockIdx.x, b = blockIdx.y;
  const int n0 = ks_*64;
  const short* qb = qc + (size_t)b*NTOK*64;
  const short* kb = kc + (size_t)b*NTOK*64;

  bf16x8 aq0 = *(const bf16x8*)(qb + (size_t)(wave*16+l16)*4096 + n0 + quad*8);
  bf16x8 aq1 = *(const bf16x8*)(qb + (size_t)(wave*16+l16)*4096 + n0 + 32 + quad*8);
  f32x4 acc[4];
  for (int nt=0;nt<4;nt++) {
    bf16x8 bk0 = *(const bf16x8*)(kb + (size_t)(nt*16+l16)*4096 + n0 + quad*8);
    bf16x8 bk1 = *(const bf16x8*)(kb + (size_t)(nt*16+l16)*4096 + n0 + 32 + quad*8);
    f32x4 z = {0.f,0.f,0.f,0.f};
    z = __builtin_amdgcn_mfma_f32_16x16x32_bf16(aq0, bk0, z, 0,0,0);
    z = __builtin_amdgcn_mfma_f32_16x16x32_bf16(aq1, bk1, z, 0,0,0);
    acc[nt] = z;
  }
  float* gp = Gpart + ((size_t)b*64 + ks_)*4096;
  for (int nt=0;nt<4;nt++)
    for (int r=0;r<4;r++)
      gp[(wave*16 + quad*4 + r)*64 + nt*16 + l16] = acc[nt][r];
}

// ---- sum 6 spatial partials + (chan G-reduce + softmax + AV row) + fusion ----
__global__ __launch_bounds__(256) void combine_fuse(const short* __restrict__ opart,
    const float* __restrict__ ml, const float* __restrict__ Gpart,
    const short* __restrict__ vc, const float* __restrict__ x,
    const float* __restrict__ pa, const float* __restrict__ pb,
    float* __restrict__ out) {
  __shared__ float sInv[64];
  __shared__ float sAtt[64];
  const int qt = blockIdx.x, b = blockIdx.y, hz = blockIdx.z, t = threadIdx.x;
  const size_t base6 = ((size_t)b*64 + qt)*6;
  if (t < 64) {
    float den = 0.f;
    for (int kg=0;kg<6;kg++) den += ml[(base6+kg)*64 + t];
    sInv[t] = 1.f/den;
    float g = 0.f;
    const float* gp = Gpart + (size_t)b*64*4096 + qt*64 + t;
    for (int ks=0; ks<64; ks++) g += gp[(size_t)ks*4096];
    float m = g;
    for (int off=1; off<64; off<<=1) m = fmaxf(m, __shfl_xor(m, off));
    float p = __builtin_amdgcn_exp2f(g - m);
    float s = p;
    for (int off=1; off<64; off<<=1) s += __shfl_xor(s, off);
    sAtt[t] = p/s;
  }
  __syncthreads();

  const int e0 = hz*2048 + t*8;
  const int q = e0 >> 6;
  const int qg = q >> 4, l16 = q & 15;
  const int seg = (t&7) >> 1, quad0 = (t&1)*2;

  float accS[8];
  for (int j=0;j<8;j++) accS[j]=0.f;
  for (int kg=0;kg<6;kg++) {
    const short* op = opart + (base6+kg)*4096 + qg*1024 + seg*256 + l16*4;
    bf16x4 c0 = *(const bf16x4*)(op + quad0*64);
    bf16x4 c1 = *(const bf16x4*)(op + (quad0+1)*64);
    for (int r=0;r<4;r++) { accS[r] += bf2f(c0[r]); accS[4+r] += bf2f(c1[r]); }
  }
  float inv = sInv[q];
  float accC[8];
  for (int j=0;j<8;j++) accC[j]=0.f;
  const short* vb = vc + (size_t)b*NTOK*64;
  for (int d=0; d<64; d++) {
    bf16x8 v = *(const bf16x8*)(vb + (size_t)d*4096 + e0);
    float a = sAtt[d];
    for (int j=0;j<8;j++) accC[j] += a*bf2f(v[j]);
  }
  const float av = pa[0], bv = pb[0];
  size_t flat = ((size_t)b*64 + qt)*4096 + e0;
  f32x4 x0 = *(const f32x4*)(x + flat);
  f32x4 x1 = *(const f32x4*)(x + flat + 4);
  f32x4 r0, r1;
  for (int j=0;j<4;j++) {
    r0[j] = bv*accS[j]*inv   + av*accC[j]   + 2.f*x0[j];
    r1[j] = bv*accS[4+j]*inv + av*accC[4+j] + 2.f*x1[j];
  }
  *(f32x4*)(out + flat)     = r0;
  *(f32x4*)(out + flat + 4) = r1;
}

extern "C" void kernel_launch(void* const* d_in, const int* in_sizes, int n_in,
                              void* d_out, int out_size, void* d_ws, size_t ws_size,
                              hipStream_t stream) {
  const float* x = (const float*)d_in[0];
  char* ws = (char*)d_ws;
  const size_t MB = 1048576;
  short* qs    = (short*)(ws + 0*MB);
  short* ks_   = (short*)(ws + 2*MB);
  short* vst   = (short*)(ws + 4*MB);
  short* qc    = (short*)(ws + 6*MB);
  short* kc    = (short*)(ws + 8*MB);
  short* vc    = (short*)(ws + 10*MB);
  short* opart = (short*)(ws + 12*MB);   // 12 MB (6 kg)
  float* ml    = (float*)(ws + 24*MB);   // 384 KB
  float* Gpart = (float*)(ws + 0*MB);    // overlays qs/ks (dead after attn_part)

  ConvArgs ca;
  ca.x = x;
  for (int i=0;i<6;i++) {
    ca.w[i]    = (const float*)d_in[1+2*i];
    ca.bias[i] = (const float*)d_in[2+2*i];
  }
  ca.out[0]=qs; ca.out[1]=ks_; ca.out[2]=vst;
  ca.out[3]=qc; ca.out[4]=kc; ca.out[5]=vc;

  hipLaunchKernelGGL(conv_qkv, dim3(256,2), dim3(256), 0, stream, ca);
  hipLaunchKernelGGL(attn_part, dim3(32,4,6), dim3(256), 0, stream, qs, ks_, vst, opart, ml);
  hipLaunchKernelGGL(chan_qk_part, dim3(64,4), dim3(256), 0, stream, qc, kc, Gpart);
  hipLaunchKernelGGL(combine_fuse, dim3(64,4,2), dim3(256), 0, stream,
                     opart, ml, Gpart, vc, x, (const float*)d_in[13], (const float*)d_in[14],
                     (float*)d_out);
}